// Round 5
// baseline (318.744 us; speedup 1.0000x reference)
//
#include <hip/hip_runtime.h>

// Problem constants (fixed by setup_inputs: T=8, N=2048, D=256)
#define T_ALL 8
#define T1    7
#define NPTS  2048
#define DD    256
#define BM    128           // src rows per block
#define BN    128           // dst cols per block (== CPS, single chunk)
#define BK    16            // k-tile per round
#define SPLIT 16            // column split factor -> grid 7*16*16 = 1792 = 7/CU
#define CPS   (NPTS / SPLIT)         // 128
#define NROUND (DD / BK)             // 16 rounds, k strictly ascending

// ws layout (floats): [0, NDF) normalized descriptors; then u64 best[T1*NPTS]
#define NDF   (T_ALL * NPTS * DD)    // 4194304 floats

__device__ __forceinline__ int swzidx(int col) {
    // element col -> stored float offset within a k-row of 128 floats:
    // slot = (col>>2) ^ ((col>>2)>>3). Bijective, <=2-way banks for all
    // read/write patterns used below.
    int s = col >> 2;
    return (((s ^ (s >> 3)) & 31) << 2) | (col & 3);
}

// monotone pack of (cos value, argmax idx) into u64 for atomicMax.
// Larger value wins; on equal value, smaller idx wins (first-occurrence).
__device__ __forceinline__ unsigned long long packVI(float v, int idx) {
    unsigned int b = __float_as_uint(v);
    b = (b & 0x80000000u) ? ~b : (b | 0x80000000u);   // order-preserving
    return ((unsigned long long)b << 32) | (unsigned int)(NPTS - 1 - idx);
}

// ---------------------------------------------------------------------------
// Kernel 1: normalize descriptors row-wise: x / max(||x||, 1e-8).
// Also clears the atomic best[] array (harness poisons ws with 0xAA once).
// ---------------------------------------------------------------------------
__global__ __launch_bounds__(256) void norm_kernel(const float* __restrict__ desc,
                                                   float* __restrict__ out,
                                                   unsigned long long* __restrict__ best) {
    int gid  = blockIdx.x * blockDim.x + threadIdx.x;
    if (gid < T1 * NPTS) best[gid] = 0ull;   // decodes below any real cos value

    int row  = gid >> 6;
    int lane = gid & 63;
    const float4 v = reinterpret_cast<const float4*>(desc)[(size_t)row * (DD / 4) + lane];
    float s = v.x * v.x + v.y * v.y + v.z * v.z + v.w * v.w;
#pragma unroll
    for (int off = 32; off >= 1; off >>= 1)
        s += __shfl_xor(s, off, 64);
    float n = fmaxf(sqrtf(s), 1e-8f);
    float4 o = make_float4(v.x / n, v.y / n, v.z / n, v.w / n);
    reinterpret_cast<float4*>(out)[(size_t)row * (DD / 4) + lane] = o;
}

// ---------------------------------------------------------------------------
// Kernel 2: fused partial GEMM (128 rows x 128 cols per block) + row
// max/argmax, double-buffered LDS (ONE barrier per round), prefetch issued
// AFTER the barrier so the barrier never drains outstanding vmcnt.
// 256 threads = 16x16, 8x8 micro-tile.
// NOTE: no min-occupancy in __launch_bounds__ — a (256,3) bound clamped
// VGPRs to 84 and spilled the accumulator (589 MB scratch writes, R3).
// ---------------------------------------------------------------------------
__global__ __launch_bounds__(256) void match_kernel(const float* __restrict__ nd,
                                                    unsigned long long* __restrict__ best) {
    __shared__ __align__(16) float smem[4 * BK * BM];  // 32 KB: A0,B0,A1,B1
    float* sA0 = smem;
    float* sB0 = sA0 + BK * BM;
    float* sA1 = sB0 + BK * BM;
    float* sB1 = sA1 + BK * BM;
    float* redV = smem;                         // [BM][17] alias (epilogue only)
    int*   redI = (int*)&smem[BM * 17];

    const int bid = blockIdx.x;                 // ((t*16)+rb)*16 + sp
    const int sp  = bid & (SPLIT - 1);
    const int rb  = (bid >> 4) & 15;
    const int t   = bid >> 8;
    const int tid = threadIdx.x;
    const int tx  = tid & 15;                   // col group: cols tx*8..+7
    const int ty  = tid >> 4;                   // row group: rows ty*8..+7

    const float* Abase = nd + ((size_t)t * NPTS + (size_t)rb * BM) * DD;
    const float* Bbase = nd + ((size_t)(t + 1) * NPTS + (size_t)sp * CPS) * DD;

    // staging geometry: per thread 2 float4 per tile (rows/cols scol, scol+64)
    const int scol = tid & 63;
    const int sk4  = tid >> 6;                  // wave-uniform
    const int w0   = swzidx(scol);
    const int w1   = swzidx(scol + 64);

    // compute-phase read offsets (float index within a k-row)
    const int aoff0 = (((ty * 2)     ^ ((ty * 2) >> 3))     & 31) << 2;
    const int aoff1 = (((ty * 2 + 1) ^ ((ty * 2 + 1) >> 3)) & 31) << 2;
    const int boff0 = (((tx * 2)     ^ ((tx * 2) >> 3))     & 31) << 2;
    const int boff1 = (((tx * 2 + 1) ^ ((tx * 2 + 1) >> 3)) & 31) << 2;

    float4 pA0, pA1, pB0, pB1;                  // in-flight staging registers
    float acc[8][8];
#pragma unroll
    for (int r = 0; r < 8; ++r)
#pragma unroll
        for (int c = 0; c < 8; ++c) acc[r][c] = 0.0f;

    auto issue = [&](int g) {                   // global -> regs for round g
        const float* Ab = Abase + g * BK + sk4 * 4;
        const float* Bb = Bbase + g * BK + sk4 * 4;
        pA0 = *reinterpret_cast<const float4*>(Ab + (size_t)scol * DD);
        pA1 = *reinterpret_cast<const float4*>(Ab + (size_t)(scol + 64) * DD);
        pB0 = *reinterpret_cast<const float4*>(Bb + (size_t)scol * DD);
        pB1 = *reinterpret_cast<const float4*>(Bb + (size_t)(scol + 64) * DD);
    };
    auto stage = [&](float* sAb, float* sBb) {  // regs -> LDS (transpose+swz)
        float* a0 = sAb + (sk4 * 4) * BM;
        a0[0 * BM + w0] = pA0.x;  a0[1 * BM + w0] = pA0.y;
        a0[2 * BM + w0] = pA0.z;  a0[3 * BM + w0] = pA0.w;
        a0[0 * BM + w1] = pA1.x;  a0[1 * BM + w1] = pA1.y;
        a0[2 * BM + w1] = pA1.z;  a0[3 * BM + w1] = pA1.w;
        float* b0 = sBb + (sk4 * 4) * BN;
        b0[0 * BN + w0] = pB0.x;  b0[1 * BN + w0] = pB0.y;
        b0[2 * BN + w0] = pB0.z;  b0[3 * BN + w0] = pB0.w;
        b0[0 * BN + w1] = pB1.x;  b0[1 * BN + w1] = pB1.y;
        b0[2 * BN + w1] = pB1.z;  b0[3 * BN + w1] = pB1.w;
    };
    auto compute = [&](const float* sAb, const float* sBb) {
#pragma unroll
        for (int kk = 0; kk < BK; ++kk) {
            float4 a0 = *reinterpret_cast<const float4*>(&sAb[kk * BM + aoff0]);
            float4 a1 = *reinterpret_cast<const float4*>(&sAb[kk * BM + aoff1]);
            float4 b0 = *reinterpret_cast<const float4*>(&sBb[kk * BN + boff0]);
            float4 b1 = *reinterpret_cast<const float4*>(&sBb[kk * BN + boff1]);
            float av[8] = {a0.x, a0.y, a0.z, a0.w, a1.x, a1.y, a1.z, a1.w};
            float bv[8] = {b0.x, b0.y, b0.z, b0.w, b1.x, b1.y, b1.z, b1.w};
#pragma unroll
            for (int r = 0; r < 8; ++r)
#pragma unroll
                for (int c = 0; c < 8; ++c)
                    acc[r][c] = fmaf(av[r], bv[c], acc[r][c]);
        }
    };

    issue(0);                                   // prologue
#pragma unroll 1
    for (int gg = 0; gg < NROUND; gg += 2) {
        // even round gg: buffer 0
        stage(sA0, sB0);                        // vmcnt waited here via pr use
        __syncthreads();                        // nothing outstanding but lgkm
        issue(gg + 1);                          // gg+1 <= 15 always
        compute(sA0, sB0);
        // odd round gg+1: buffer 1
        stage(sA1, sB1);
        __syncthreads();
        if (gg + 2 < NROUND) issue(gg + 2);
        compute(sA1, sB1);
    }

    // ---- fold acc into per-thread (val, idx); k-order was 0..255 in sequence
    float bestV[8];
    int   bestI[8];
    const int colbase = sp * CPS + tx * 8;
#pragma unroll
    for (int r = 0; r < 8; ++r) { bestV[r] = -3.0e38f; bestI[r] = 0; }
#pragma unroll
    for (int c = 0; c < 8; ++c) {
        const int col = colbase + c;            // ascending -> '>' keeps first
#pragma unroll
        for (int r = 0; r < 8; ++r)
            if (acc[r][c] > bestV[r]) { bestV[r] = acc[r][c]; bestI[r] = col; }
    }

    // ---- cross-thread reduction: 16 col-group partials per row ----
    __syncthreads();                            // all compute done; alias LDS
#pragma unroll
    for (int r = 0; r < 8; ++r) {
        redV[(ty * 8 + r) * 17 + tx] = bestV[r];
        redI[(ty * 8 + r) * 17 + tx] = bestI[r];
    }
    __syncthreads();

    if (tid < BM) {
        float bv = redV[tid * 17];
        int   bi = redI[tid * 17];
#pragma unroll
        for (int jj = 1; jj < 16; ++jj) {
            float v  = redV[tid * 17 + jj];
            int   ix = redI[tid * 17 + jj];
            if (v > bv || (v == bv && ix < bi)) { bv = v; bi = ix; }
        }
        // order-independent cross-block merge (deterministic)
        atomicMax(&best[t * NPTS + rb * BM + tid], packVI(bv, bi));
    }
}

// ---------------------------------------------------------------------------
// Kernel 3: unpack best[], gather matched points, write outputs.
// ---------------------------------------------------------------------------
__global__ __launch_bounds__(256) void final_kernel(const unsigned long long* __restrict__ best,
                                                    const float* __restrict__ pts,
                                                    float* __restrict__ out) {
    int r = blockIdx.x * 256 + threadIdx.x;     // 0 .. T1*NPTS-1
    int t = r >> 11;
    unsigned long long p = best[r];
    int idx = NPTS - 1 - (int)(p & 0xFFFFFFFFull);
    unsigned int b = (unsigned int)(p >> 32);
    b = (b & 0x80000000u) ? (b & 0x7FFFFFFFu) : ~b;   // inverse transform
    out[(size_t)T1 * NPTS * 2 + r] = __uint_as_float(b);
    const float* q = pts + ((size_t)(t + 1) * NPTS + idx) * 2;
    out[(size_t)r * 2 + 0] = q[0];
    out[(size_t)r * 2 + 1] = q[1];
}

// ---------------------------------------------------------------------------
extern "C" void kernel_launch(void* const* d_in, const int* in_sizes, int n_in,
                              void* d_out, int out_size, void* d_ws, size_t ws_size,
                              hipStream_t stream) {
    const float* desc = (const float*)d_in[0];   // [8, 2048, 256] fp32
    const float* pts  = (const float*)d_in[1];   // [8, 2048, 2]   fp32
    float* nd = (float*)d_ws;                    // 16 MB normalized copy
    unsigned long long* best = (unsigned long long*)(nd + NDF);  // 112 KB

    norm_kernel<<<(T_ALL * NPTS) / 4, 256, 0, stream>>>(desc, nd, best);
    match_kernel<<<T1 * 16 * SPLIT, 256, 0, stream>>>(nd, best);
    final_kernel<<<(T1 * NPTS) / 256, 256, 0, stream>>>(best, pts, (float*)d_out);
}

// Round 6
// 235.430 us; speedup vs baseline: 1.3539x; 1.3539x over previous
//
#include <hip/hip_runtime.h>

// Problem constants (fixed by setup_inputs: T=8, N=2048, D=256)
#define T_ALL 8
#define T1    7
#define NPTS  2048
#define DD    256
#define BM    128           // src rows per block
#define BN    256           // dst cols per block
#define BK    16            // k-tile per round
#define SPLIT 8             // 2048/256 cols -> grid 7*16*8 = 896
#define NROUND (DD / BK)    // 16 rounds, k strictly ascending

// ws layout (floats): [0, NDF) normalized descriptors; then u64 best[T1*NPTS]
#define NDF   (T_ALL * NPTS * DD)    // 4194304 floats

// slot swizzle (slot = 16B unit index within a k-row); bijective, spreads banks
__device__ __forceinline__ int swzs(int s) { return s ^ ((s >> 3) & 7); }

// monotone pack of (cos value, argmax idx) into u64 for atomicMax.
// Larger value wins; on equal value, smaller idx wins (first-occurrence).
__device__ __forceinline__ unsigned long long packVI(float v, int idx) {
    unsigned int b = __float_as_uint(v);
    b = (b & 0x80000000u) ? ~b : (b | 0x80000000u);   // order-preserving
    return ((unsigned long long)b << 32) | (unsigned int)(NPTS - 1 - idx);
}

// ---------------------------------------------------------------------------
// Kernel 1: normalize descriptors row-wise: x / max(||x||, 1e-8).
// Also clears the atomic best[] array (ws is poisoned 0xAA once by harness).
// ---------------------------------------------------------------------------
__global__ __launch_bounds__(256) void norm_kernel(const float* __restrict__ desc,
                                                   float* __restrict__ out,
                                                   unsigned long long* __restrict__ best) {
    int gid  = blockIdx.x * blockDim.x + threadIdx.x;
    if (gid < T1 * NPTS) best[gid] = 0ull;   // below any real packed cos

    int row  = gid >> 6;
    int lane = gid & 63;
    const float4 v = reinterpret_cast<const float4*>(desc)[(size_t)row * (DD / 4) + lane];
    float s = v.x * v.x + v.y * v.y + v.z * v.z + v.w * v.w;
#pragma unroll
    for (int off = 32; off >= 1; off >>= 1)
        s += __shfl_xor(s, off, 64);
    float n = fmaxf(sqrtf(s), 1e-8f);
    float4 o = make_float4(v.x / n, v.y / n, v.z / n, v.w / n);
    reinterpret_cast<float4*>(out)[(size_t)row * (DD / 4) + lane] = o;
}

// ---------------------------------------------------------------------------
// Kernel 2: fused partial GEMM (128 rows x 256 cols per block) + row
// max/argmax. 256 threads = 16(ty) x 16(tx); per-thread 8 rows x 16 cols
// (0.375 LDS-bytes/FLOP -> under the 69 TB/s LDS ceiling; 8x8's 0.5 was
// LDS-read-bound at ~112 us). R4 round structure: single LDS buffer,
// stage -> barrier -> issue-next -> compute -> barrier.
// NOTE: no min-occupancy bound — (256,3) clamped VGPR to 84 and spilled (R3).
// ---------------------------------------------------------------------------
__global__ __launch_bounds__(256) void match_kernel(const float* __restrict__ nd,
                                                    unsigned long long* __restrict__ best) {
    __shared__ __align__(16) float smem[BK * BM + BK * BN];   // 8KB + 16KB
    float* sA = smem;                        // [BK][128] k-major, slot-swizzled
    float* sB = smem + BK * BM;              // [BK][256] k-major, slot-swizzled
    float* redV = smem;                      // [128][17] alias (epilogue only)
    int*   redI = (int*)&smem[BM * 17];

    const int bid = blockIdx.x;              // ((t*16)+rb)*8 + sp
    const int sp  = bid & (SPLIT - 1);
    const int rb  = (bid >> 3) & 15;
    const int t   = bid >> 7;
    const int tid = threadIdx.x;
    const int tx  = tid & 15;                // col group: cols tx*16..+15
    const int ty  = tid >> 4;                // row group: rows ty*8..+7

    const float* Abase = nd + ((size_t)t * NPTS + (size_t)rb * BM) * DD;
    const float* Bbase = nd + ((size_t)(t + 1) * NPTS + (size_t)sp * BN) * DD;

    // ---- staging geometry ----
    // A: thread covers row (tid&127), k4-slots ak4, ak4+1  (32B contiguous)
    const int arow = tid & 127;
    const int ak4  = (tid >> 7) * 2;         // 0 or 2
    const int afs  = 4 * swzs(arow >> 2) + (arow & 3);   // float slot in sA row
    // B: thread covers col tid, k4-slots 0..3 (64B contiguous)
    const int bcol = tid;
    const int bfs  = 4 * swzs(bcol >> 2) + (bcol & 3);   // float slot in sB row

    // ---- compute-phase read offsets (16B-aligned float offsets) ----
    const int aoff0 = 4 * swzs(2 * ty);
    const int aoff1 = 4 * swzs(2 * ty + 1);
    int boff[4];
#pragma unroll
    for (int q = 0; q < 4; ++q) boff[q] = 4 * swzs(4 * tx + q);

    float4 pA0, pA1, pB[4];                  // in-flight staging registers
    float acc[8][16];
#pragma unroll
    for (int r = 0; r < 8; ++r)
#pragma unroll
        for (int c = 0; c < 16; ++c) acc[r][c] = 0.0f;

    auto issue = [&](int g) {                // global -> regs for round g
        const float* Ap = Abase + (size_t)arow * DD + g * BK + ak4 * 4;
        pA0 = *reinterpret_cast<const float4*>(Ap);
        pA1 = *reinterpret_cast<const float4*>(Ap + 4);
        const float* Bp = Bbase + (size_t)bcol * DD + g * BK;
#pragma unroll
        for (int q = 0; q < 4; ++q)
            pB[q] = *reinterpret_cast<const float4*>(Bp + q * 4);
    };
    auto stage = [&]() {                     // regs -> LDS (transpose + swizzle)
        float* a = sA + (ak4 * 4) * BM + afs;
        a[0 * BM] = pA0.x;  a[1 * BM] = pA0.y;  a[2 * BM] = pA0.z;  a[3 * BM] = pA0.w;
        a[4 * BM] = pA1.x;  a[5 * BM] = pA1.y;  a[6 * BM] = pA1.z;  a[7 * BM] = pA1.w;
        float* b = sB + bfs;
#pragma unroll
        for (int q = 0; q < 4; ++q) {
            float* bq = b + (q * 4) * BN;
            bq[0 * BN] = pB[q].x;  bq[1 * BN] = pB[q].y;
            bq[2 * BN] = pB[q].z;  bq[3 * BN] = pB[q].w;
        }
    };

    issue(0);                                // prologue
#pragma unroll 1
    for (int g = 0; g < NROUND; ++g) {
        stage();                             // waits vmcnt via register use
        __syncthreads();                     // tiles ready
        if (g + 1 < NROUND) issue(g + 1);    // loads fly under compute
#pragma unroll
        for (int kk = 0; kk < BK; ++kk) {
            const float* sak = sA + kk * BM;
            const float* sbk = sB + kk * BN;
            float4 a0 = *reinterpret_cast<const float4*>(sak + aoff0);
            float4 a1 = *reinterpret_cast<const float4*>(sak + aoff1);
            float av[8] = {a0.x, a0.y, a0.z, a0.w, a1.x, a1.y, a1.z, a1.w};
#pragma unroll
            for (int q = 0; q < 4; ++q) {
                float4 bq = *reinterpret_cast<const float4*>(sbk + boff[q]);
                float bv[4] = {bq.x, bq.y, bq.z, bq.w};
#pragma unroll
                for (int r = 0; r < 8; ++r)
#pragma unroll
                    for (int e = 0; e < 4; ++e)
                        acc[r][q * 4 + e] = fmaf(av[r], bv[e], acc[r][q * 4 + e]);
            }
        }
        __syncthreads();                     // compute done before next stage
    }

    // ---- fold acc into per-thread (val, idx); cols ascending ----
    float bestV[8];
    int   bestI[8];
    const int colbase = sp * BN + tx * 16;
#pragma unroll
    for (int r = 0; r < 8; ++r) { bestV[r] = -3.0e38f; bestI[r] = 0; }
#pragma unroll
    for (int c = 0; c < 16; ++c) {
        const int col = colbase + c;         // ascending -> '>' keeps first
#pragma unroll
        for (int r = 0; r < 8; ++r)
            if (acc[r][c] > bestV[r]) { bestV[r] = acc[r][c]; bestI[r] = col; }
    }

    // ---- cross-thread reduction: 16 tx partials per row ----
    __syncthreads();                         // compute done; alias LDS
#pragma unroll
    for (int r = 0; r < 8; ++r) {
        redV[(ty * 8 + r) * 17 + tx] = bestV[r];
        redI[(ty * 8 + r) * 17 + tx] = bestI[r];
    }
    __syncthreads();

    if (tid < BM) {
        float bv = redV[tid * 17];
        int   bi = redI[tid * 17];
#pragma unroll
        for (int jj = 1; jj < 16; ++jj) {
            float v  = redV[tid * 17 + jj];
            int   ix = redI[tid * 17 + jj];
            if (v > bv || (v == bv && ix < bi)) { bv = v; bi = ix; }
        }
        // order-independent cross-block merge (deterministic)
        atomicMax(&best[t * NPTS + rb * BM + tid], packVI(bv, bi));
    }
}

// ---------------------------------------------------------------------------
// Kernel 3: unpack best[], gather matched points, write outputs.
// ---------------------------------------------------------------------------
__global__ __launch_bounds__(256) void final_kernel(const unsigned long long* __restrict__ best,
                                                    const float* __restrict__ pts,
                                                    float* __restrict__ out) {
    int r = blockIdx.x * 256 + threadIdx.x;  // 0 .. T1*NPTS-1
    int t = r >> 11;
    unsigned long long p = best[r];
    int idx = NPTS - 1 - (int)(p & 0xFFFFFFFFull);
    unsigned int b = (unsigned int)(p >> 32);
    b = (b & 0x80000000u) ? (b & 0x7FFFFFFFu) : ~b;   // inverse transform
    out[(size_t)T1 * NPTS * 2 + r] = __uint_as_float(b);
    const float* q = pts + ((size_t)(t + 1) * NPTS + idx) * 2;
    out[(size_t)r * 2 + 0] = q[0];
    out[(size_t)r * 2 + 1] = q[1];
}

// ---------------------------------------------------------------------------
extern "C" void kernel_launch(void* const* d_in, const int* in_sizes, int n_in,
                              void* d_out, int out_size, void* d_ws, size_t ws_size,
                              hipStream_t stream) {
    const float* desc = (const float*)d_in[0];   // [8, 2048, 256] fp32
    const float* pts  = (const float*)d_in[1];   // [8, 2048, 2]   fp32
    float* nd = (float*)d_ws;                    // 16 MB normalized copy
    unsigned long long* best = (unsigned long long*)(nd + NDF);  // 112 KB

    norm_kernel<<<(T_ALL * NPTS) / 4, 256, 0, stream>>>(desc, nd, best);
    match_kernel<<<T1 * 16 * SPLIT, 256, 0, stream>>>(nd, best);
    final_kernel<<<(T1 * NPTS) / 256, 256, 0, stream>>>(best, pts, (float*)d_out);
}